// Round 3
// baseline (84.005 us; speedup 1.0000x reference)
//
#include <hip/hip_runtime.h>

// BayesLinearEMP: out[b,o] = dot(W[mode[b],o,:], x[b,:]) + bias[mode[b],o]
// B=128, I=O=2048, M=20, fp32. Memory-bound: 335 MB weight stream (floor ~53us).
// Single fused kernel: each block = (mode, 16-row O-tile); rebuilds its mode's
// sample list from mode_idx via deterministic ballot/prefix grouping, then
// streams weights exactly once (nontemporal), fanning each row out to all
// samples of the mode. Branch-free specialized bodies per sample-count.

#define M_MODES 20
#define B_SAMP  128
#define I_DIM   2048
#define O_DIM   2048
#define RPW     4             // output rows per wave
#define ROWS_PER_BLOCK 16     // 4 waves * RPW
#define OTILES  (O_DIM / ROWS_PER_BLOCK)    // 128

typedef float f32x4 __attribute__((ext_vector_type(4)));

// ---- x-load + FMA for a sub-group of <=8 samples ---------------------------
template<int SC, int S0>
__device__ __forceinline__ void fma8(const float* const (&xb)[SC], int i,
                                     const f32x4 (&w4)[RPW],
                                     float (&acc)[RPW][SC]) {
    constexpr int G = (SC - S0) < 8 ? (SC - S0) : 8;
    f32x4 xv[G];
    #pragma unroll
    for (int s = 0; s < G; ++s)
        xv[s] = *reinterpret_cast<const f32x4*>(xb[S0 + s] + i);
    #pragma unroll
    for (int s = 0; s < G; ++s)
        #pragma unroll
        for (int r = 0; r < RPW; ++r)
            acc[r][S0 + s] += w4[r][0] * xv[s][0] + w4[r][1] * xv[s][1]
                            + w4[r][2] * xv[s][2] + w4[r][3] * xv[s][3];
}

constexpr int next_pow2(int n) {
    int p = 1;
    while (p < n) p <<= 1;
    return p;
}

// ---- branch-free body for SC samples ---------------------------------------
template<int SC>
__device__ __forceinline__ void bmv_body(const float* __restrict__ x,
                                         const float* __restrict__ wrow,
                                         const float* __restrict__ biases,
                                         const int*   list,   // LDS
                                         int scount, int m, int o0, int lane,
                                         float* __restrict__ out) {
    // wave-uniform x row bases -> SGPRs
    const float* xb[SC];
    #pragma unroll
    for (int s = 0; s < SC; ++s) {
        const int ss  = (s < scount) ? s : (scount - 1);   // clamp padding
        int idx = list[ss];
        idx = __builtin_amdgcn_readfirstlane(idx);
        xb[s] = x + (size_t)idx * I_DIM;
    }

    float acc[RPW][SC];
    #pragma unroll
    for (int r = 0; r < RPW; ++r)
        #pragma unroll
        for (int s = 0; s < SC; ++s)
            acc[r][s] = 0.0f;

    // stream I: lane l owns float4 at i + l*4 (+256 for second half).
    // CH=2 (for small SC) keeps 8 nontemporal weight loads in flight.
    constexpr int CH = (SC <= 8) ? 2 : 1;
    for (int i = lane * 4; i < I_DIM; i += 256 * CH) {
        f32x4 w4[CH][RPW];
        #pragma unroll
        for (int h = 0; h < CH; ++h)
            #pragma unroll
            for (int r = 0; r < RPW; ++r)
                w4[h][r] = __builtin_nontemporal_load(
                    reinterpret_cast<const f32x4*>(wrow + (size_t)r * I_DIM + i + h * 256));
        #pragma unroll
        for (int h = 0; h < CH; ++h) {
            fma8<SC, 0>(xb, i + h * 256, w4[h], acc);
            if constexpr (SC > 8) fma8<SC, 8>(xb, i + h * 256, w4[h], acc);
        }
    }

    // merge-tree reduction over NVP (pow2-padded) values; each stage halves
    // both the live value count and the un-summed lane distance.
    constexpr int NV  = RPW * SC;
    constexpr int NVP = next_pow2(NV);          // <= 64
    float v[NVP];
    #pragma unroll
    for (int j = 0; j < NVP; ++j)
        v[j] = (j < NV) ? acc[j & (RPW - 1)][j >> 2] : 0.0f;   // j = s*4 + r
    int D = 32;
    #pragma unroll
    for (int n = NVP; n > 1; n >>= 1, D >>= 1) {
        #pragma unroll
        for (int j = 0; j < n / 2; ++j) {
            const float a = v[j], b = v[j + n / 2];
            const bool hi = (lane & D) != 0;
            const float sel = hi ? b : a;
            const float oth = __shfl_xor(hi ? a : b, D, 64);
            v[j] = sel + oth;
        }
    }
    #pragma unroll
    for (int Dr = 64 / NVP / 2; Dr >= 1; Dr >>= 1)   // residual butterfly
        v[0] += __shfl_xor(v[0], Dr, 64);

    // store: lane l -> value j = l/rep, j = s*4 + r
    constexpr int rep = 64 / NVP;
    if ((lane & (rep - 1)) == 0) {
        const int j = lane / rep;
        const int s = j >> 2;
        const int r = j & (RPW - 1);
        if (s < scount) {
            const int idx = list[s];
            out[(size_t)idx * O_DIM + (o0 + r)] =
                v[0] + biases[(size_t)m * O_DIM + o0 + r];
        }
    }
}

// ---- fused kernel ----------------------------------------------------------
__global__ __launch_bounds__(256, 3)
void bmv_kernel(const float* __restrict__ x,
                const float* __restrict__ weights,
                const float* __restrict__ biases,
                const int*   __restrict__ mode_idx,
                float*       __restrict__ out) {
    const int m  = blockIdx.x / OTILES;
    const int ot = blockIdx.x % OTILES;

    const int tid  = threadIdx.x;
    const int wv   = tid >> 6;
    const int lane = tid & 63;

    // deterministic in-block grouping: stable ballot/prefix over mode_idx
    __shared__ int s_list[B_SAMP];
    __shared__ int s_wcnt[2];
    int match = 0, prefix = 0;
    if (tid < B_SAMP) {                      // waves 0 and 1, fully active
        match  = (mode_idx[tid] == m);
        const unsigned long long mask = __ballot(match);
        prefix = __popcll(mask & ((1ull << lane) - 1));
        if (lane == 0) s_wcnt[wv] = __popcll(mask);
    }
    __syncthreads();
    const int cnt = s_wcnt[0] + s_wcnt[1];
    if (match) s_list[prefix + (wv ? s_wcnt[0] : 0)] = tid;
    __syncthreads();
    if (cnt == 0) return;

    const int o0   = ot * ROWS_PER_BLOCK + wv * RPW;
    const float* wrow = weights + ((size_t)m * O_DIM + o0) * I_DIM;

    for (int s0 = 0; s0 < cnt; s0 += 16) {
        const int sc = min(cnt - s0, 16);
        const int* list = s_list + s0;
        switch (sc) {
            case 1:  bmv_body<1> (x, wrow, biases, list, sc, m, o0, lane, out); break;
            case 2:  bmv_body<2> (x, wrow, biases, list, sc, m, o0, lane, out); break;
            case 3:  bmv_body<3> (x, wrow, biases, list, sc, m, o0, lane, out); break;
            case 4:  bmv_body<4> (x, wrow, biases, list, sc, m, o0, lane, out); break;
            case 5:  bmv_body<5> (x, wrow, biases, list, sc, m, o0, lane, out); break;
            case 6:  bmv_body<6> (x, wrow, biases, list, sc, m, o0, lane, out); break;
            case 7:  bmv_body<7> (x, wrow, biases, list, sc, m, o0, lane, out); break;
            case 8:  bmv_body<8> (x, wrow, biases, list, sc, m, o0, lane, out); break;
            case 9:
            case 10: bmv_body<10>(x, wrow, biases, list, sc, m, o0, lane, out); break;
            case 11:
            case 12: bmv_body<12>(x, wrow, biases, list, sc, m, o0, lane, out); break;
            case 13:
            case 14: bmv_body<14>(x, wrow, biases, list, sc, m, o0, lane, out); break;
            default: bmv_body<16>(x, wrow, biases, list, sc, m, o0, lane, out); break;
        }
    }
}

extern "C" void kernel_launch(void* const* d_in, const int* in_sizes, int n_in,
                              void* d_out, int out_size, void* d_ws, size_t ws_size,
                              hipStream_t stream) {
    const float* x        = (const float*)d_in[0];
    const float* weights  = (const float*)d_in[1];
    const float* biases   = (const float*)d_in[2];
    const int*   mode_idx = (const int*)d_in[3];
    float* out = (float*)d_out;

    bmv_kernel<<<M_MODES * OTILES, 256, 0, stream>>>(x, weights, biases,
                                                     mode_idx, out);
}